// Round 1
// baseline (5406.036 us; speedup 1.0000x reference)
//
#include <hip/hip_runtime.h>
#include <hip/hip_bf16.h>

typedef unsigned short u16;
typedef short bf16x8 __attribute__((ext_vector_type(8)));
typedef float f32x4 __attribute__((ext_vector_type(4)));

// ---------- bf16 helpers ----------
__device__ inline float bflo(unsigned int w) { union { float f; unsigned int i; } c; c.i = w << 16; return c.f; }
__device__ inline float bfhi(unsigned int w) { union { float f; unsigned int i; } c; c.i = w & 0xffff0000u; return c.f; }
__device__ inline u16 f2bf(float f) {
    union { float f; unsigned int i; } c; c.f = f;
    unsigned int r = c.i + 0x7FFFu + ((c.i >> 16) & 1u);  // RNE
    return (u16)(r >> 16);
}

__device__ inline float wave_sum(float v) {
#pragma unroll
    for (int off = 32; off; off >>= 1) v += __shfl_down(v, off);
    return v;
}

// async global->LDS, 16B per lane. LDS dest = wave-uniform base + lane*16.
__device__ inline void gload16(const void* g, void* l) {
    __builtin_amdgcn_global_load_lds((const __attribute__((address_space(1))) void*)g,
                                     (__attribute__((address_space(3))) void*)l, 16, 0, 0);
}

// ---------- convert token_emb -> bf16 (V*D = 4096*1024) ----------
__global__ __launch_bounds__(256) void k_cvt(const float* __restrict__ in, u16* __restrict__ out) {
    int i = blockIdx.x * 256 + threadIdx.x;  // over n/4
    float4 v = ((const float4*)in)[i];
    ushort4 o;
    o.x = f2bf(v.x); o.y = f2bf(v.y); o.z = f2bf(v.z); o.w = f2bf(v.w);
    ((ushort4*)out)[i] = o;
}

// ---------- transpose + convert: in fp32 (R,C) -> out bf16 (C,R), z = layer ----------
__global__ __launch_bounds__(256) void k_transpose(const float* __restrict__ in, u16* __restrict__ out, int R, int C) {
    __shared__ float tile[32][33];
    const float* inL = in + (size_t)blockIdx.z * R * C;
    u16* outL = out + (size_t)blockIdx.z * R * C;
    int cb = blockIdx.x * 32, rb = blockIdx.y * 32;
    int tx = threadIdx.x, ty = threadIdx.y;  // (32,8)
#pragma unroll
    for (int i = 0; i < 32; i += 8)
        tile[ty + i][tx] = inL[(size_t)(rb + ty + i) * C + cb + tx];
    __syncthreads();
#pragma unroll
    for (int i = 0; i < 32; i += 8)
        outL[(size_t)(cb + ty + i) * R + rb + tx] = f2bf(tile[tx][ty + i]);
}

// ---------- embedding ----------
__global__ __launch_bounds__(256) void k_embed(const int* __restrict__ ids, const float* __restrict__ emb,
                                               const float* __restrict__ pos, float* __restrict__ x) {
    int i = blockIdx.x * 256 + threadIdx.x;
    int m = i >> 8;
    int d4 = i & 255;
    int t = m & 2047;
    int id = ids[m];
    float4 e = ((const float4*)(emb + (size_t)id * 1024))[d4];
    float4 p = ((const float4*)(pos + (size_t)t * 1024))[d4];
    float4 r; r.x = e.x + p.x; r.y = e.y + p.y; r.z = e.z + p.z; r.w = e.w + p.w;
    ((float4*)(x + (size_t)m * 1024))[d4] = r;
}

// ---------- layernorm: fp32 in (row of 1024) -> bf16 out ----------
__global__ __launch_bounds__(256) void k_ln(const float* __restrict__ in, const float* __restrict__ w,
                                            const float* __restrict__ b, u16* __restrict__ out) {
    int row = blockIdx.x, tid = threadIdx.x;
    float4 v = ((const float4*)(in + (size_t)row * 1024))[tid];
    float s = v.x + v.y + v.z + v.w;
    float ss = v.x * v.x + v.y * v.y + v.z * v.z + v.w * v.w;
    s = wave_sum(s); ss = wave_sum(ss);
    __shared__ float rs[4], rss[4];
    int wid = tid >> 6, lane = tid & 63;
    if (lane == 0) { rs[wid] = s; rss[wid] = ss; }
    __syncthreads();
    s = rs[0] + rs[1] + rs[2] + rs[3];
    ss = rss[0] + rss[1] + rss[2] + rss[3];
    float mu = s * (1.0f / 1024.0f);
    float var = ss * (1.0f / 1024.0f) - mu * mu;
    float inv = rsqrtf(var + 1e-5f);
    float4 wv = ((const float4*)w)[tid], bv = ((const float4*)b)[tid];
    ushort4 o;
    o.x = f2bf((v.x - mu) * inv * wv.x + bv.x);
    o.y = f2bf((v.y - mu) * inv * wv.y + bv.y);
    o.z = f2bf((v.z - mu) * inv * wv.z + bv.z);
    o.w = f2bf((v.w - mu) * inv * wv.w + bv.w);
    *(ushort4*)(out + (size_t)row * 1024 + tid * 4) = o;
}

// ---------- MFMA GEMM: C(M,N) = A(M,K) @ Bt(N,K)^T [+bias][gelu][+res] ----------
// Staging via global_load_lds width=16 (ladder step 3). LDS layout is linear in tid:
// ldsA byte offset = tid*16 == (wave*64 + lane)*16, so dest = wave base + lane*16.
template <bool OUT_BF16, bool GELU, bool RES, bool BIAS>
__global__ __launch_bounds__(256, 2) void k_gemm(const u16* __restrict__ A, const u16* __restrict__ Bt,
                                                 const float* __restrict__ bias, const float* __restrict__ res,
                                                 float* __restrict__ outF, u16* __restrict__ outB,
                                                 int M, int N, int K) {
    __shared__ __align__(16) u16 ldsA[128 * 32];
    __shared__ __align__(16) u16 ldsB[128 * 32];
    int tid = threadIdx.x;
    int wave = tid >> 6, lane = tid & 63;
    int quad = lane >> 4, l15 = lane & 15;
    int m0 = blockIdx.y * 128, n0 = blockIdx.x * 128;
    int wm = (wave >> 1) * 64, wn = (wave & 1) * 64;

    f32x4 acc[4][4];
#pragma unroll
    for (int i = 0; i < 4; i++)
#pragma unroll
        for (int j = 0; j < 4; j++) acc[i][j] = (f32x4){0.f, 0.f, 0.f, 0.f};

    int r0 = tid >> 2, c0 = (tid & 3) * 8;
    const size_t half = (size_t)64 * K;
    const u16* pa0 = A + (size_t)(m0 + r0) * K + c0;
    const u16* pb0 = Bt + (size_t)(n0 + r0) * K + c0;
    u16* la = ldsA + (tid & 0xC0) * 8;  // wave * 512 (u16) = wave * 1KB
    u16* lb = ldsB + (tid & 0xC0) * 8;

    for (int k0 = 0; k0 < K; k0 += 32) {
        __syncthreads();  // prior tile's ds_reads complete before overwrite
        gload16(pa0 + k0, la);
        gload16(pa0 + half + k0, la + 2048);
        gload16(pb0 + k0, lb);
        gload16(pb0 + half + k0, lb + 2048);
        __syncthreads();  // drains vmcnt: LDS tile ready
        bf16x8 af[4], bfr[4];
#pragma unroll
        for (int i = 0; i < 4; i++) af[i] = *(const bf16x8*)(ldsA + (wm + i * 16 + l15) * 32 + quad * 8);
#pragma unroll
        for (int j = 0; j < 4; j++) bfr[j] = *(const bf16x8*)(ldsB + (wn + j * 16 + l15) * 32 + quad * 8);
#pragma unroll
        for (int i = 0; i < 4; i++)
#pragma unroll
            for (int j = 0; j < 4; j++)
                acc[i][j] = __builtin_amdgcn_mfma_f32_16x16x32_bf16(af[i], bfr[j], acc[i][j], 0, 0, 0);
    }

#pragma unroll
    for (int j = 0; j < 4; j++) {
        int col = n0 + wn + j * 16 + l15;
        float bj = BIAS ? bias[col] : 0.f;
#pragma unroll
        for (int i = 0; i < 4; i++) {
#pragma unroll
            for (int r = 0; r < 4; r++) {
                int row = m0 + wm + i * 16 + quad * 4 + r;
                float v = acc[i][j][r] + bj;
                if (GELU) v = 0.5f * v * (1.0f + erff(v * 0.70710678f));
                if (RES) v += res[(size_t)row * N + col];
                if (OUT_BF16) outB[(size_t)row * N + col] = f2bf(v);
                else outF[(size_t)row * N + col] = v;
            }
        }
    }
}

// ---------- MFMA flash attention ----------
// qkv bf16 (B*T, 3072): q at h*64, k at 1024+h*64, v at 2048+h*64. out bf16 (B*T, 1024).
// Block: 256 thr = 4 waves; handles (b,h) x 128 Q rows (wave w -> 32 rows).
// K-tiles of 64. LDS stride 72 (16B-aligned rows, no superbank alias).
// launch_bounds(256,4): cap unified VGPR+AGPR at 128 -> 4 blocks/CU resident
// (LDS 36864B allows exactly 4). Attacks the measured 14.7% occupancy.
__global__ __launch_bounds__(256, 4) void k_attn(const u16* __restrict__ qkv, u16* __restrict__ out) {
    const int b = blockIdx.y >> 4, h = blockIdx.y & 15;
    const int qt = gridDim.x - 1 - blockIdx.x;  // heavy tiles first
    const int q0 = qt * 128;
    const int tid = threadIdx.x;
    const int wave = tid >> 6, lane = tid & 63;
    const int quad = lane >> 4, l15 = lane & 15;
    const int wrow = q0 + wave * 32;

    __shared__ __align__(16) u16 Klds[64 * 72];
    __shared__ __align__(16) u16 Vt[64 * 72];        // Vt[d][krow]
    __shared__ __align__(16) u16 Plds[4][32 * 72];   // wave-private

    const u16* base = qkv + (size_t)b * 2048 * 3072 + h * 64;

    // Q fragments (A-layout): rows wrow+i*16+l15, k = kc*32+quad*8
    bf16x8 qf[2][2];
#pragma unroll
    for (int i = 0; i < 2; i++)
#pragma unroll
        for (int kc = 0; kc < 2; kc++)
            qf[i][kc] = *(const bf16x8*)(base + (size_t)(wrow + i * 16 + l15) * 3072 + kc * 32 + quad * 8);

    f32x4 o[2][4];
#pragma unroll
    for (int i = 0; i < 2; i++)
#pragma unroll
        for (int jd = 0; jd < 4; jd++) o[i][jd] = (f32x4){0.f, 0.f, 0.f, 0.f};
    float mrow[2][4], lrow[2][4];
#pragma unroll
    for (int i = 0; i < 2; i++)
#pragma unroll
        for (int r = 0; r < 4; r++) { mrow[i][r] = -3e38f; lrow[i][r] = 0.f; }

    // staging assignments
    const int kk_ = tid >> 2, kc0 = (tid & 3) * 16;  // K: row kk_, cols kc0..kc0+15
    const int vk = tid & 63, vc = (tid >> 6) * 16;   // V: row vk, cols vc..vc+15 (transposed write)

    const int ktiles = 2 * (qt + 1);
    for (int t = 0; t < ktiles; t++) {
        const int kt = t * 64;
        __syncthreads();
        {
            const u16* kp = base + 1024 + (size_t)(kt + kk_) * 3072 + kc0;
            uint4 a = *(const uint4*)kp;
            uint4 c = *(const uint4*)(kp + 8);
            *(uint4*)(Klds + kk_ * 72 + kc0) = a;
            *(uint4*)(Klds + kk_ * 72 + kc0 + 8) = c;
            const u16* vp = base + 2048 + (size_t)(kt + vk) * 3072 + vc;
            uint4 v0 = *(const uint4*)vp;
            uint4 v1 = *(const uint4*)(vp + 8);
            u16 tmp[16];
            *(uint4*)tmp = v0; *(uint4*)(tmp + 8) = v1;
#pragma unroll
            for (int e = 0; e < 16; e++) Vt[(vc + e) * 72 + vk] = tmp[e];
        }
        __syncthreads();

        if (kt <= wrow + 31) {
            // S = Q @ K^T
            f32x4 s[2][4];
#pragma unroll
            for (int i = 0; i < 2; i++)
#pragma unroll
                for (int j = 0; j < 4; j++) s[i][j] = (f32x4){0.f, 0.f, 0.f, 0.f};
#pragma unroll
            for (int kc = 0; kc < 2; kc++) {
                bf16x8 bf[4];
#pragma unroll
                for (int j = 0; j < 4; j++)
                    bf[j] = *(const bf16x8*)(Klds + (j * 16 + l15) * 72 + kc * 32 + quad * 8);
#pragma unroll
                for (int i = 0; i < 2; i++)
#pragma unroll
                    for (int j = 0; j < 4; j++)
                        s[i][j] = __builtin_amdgcn_mfma_f32_16x16x32_bf16(qf[i][kc], bf[j], s[i][j], 0, 0, 0);
            }
            const bool partial = (kt + 63 > wrow);  // tile crosses the diagonal for this wave
#pragma unroll
            for (int i = 0; i < 2; i++)
#pragma unroll
                for (int j = 0; j < 4; j++)
#pragma unroll
                    for (int r = 0; r < 4; r++) {
                        float v = s[i][j][r] * 0.125f;
                        if (partial) {
                            int row = wrow + i * 16 + quad * 4 + r;
                            int col = kt + j * 16 + l15;
                            if (col > row) v = -3e30f;
                        }
                        s[i][j][r] = v;
                    }
            // online softmax per row (i,r); row constant across the 16-lane col group
            u16* pw = Plds[wave];
#pragma unroll
            for (int i = 0; i < 2; i++)
#pragma unroll
                for (int r = 0; r < 4; r++) {
                    float mx = fmaxf(fmaxf(s[i][0][r], s[i][1][r]), fmaxf(s[i][2][r], s[i][3][r]));
                    mx = fmaxf(mx, __shfl_xor(mx, 1));
                    mx = fmaxf(mx, __shfl_xor(mx, 2));
                    mx = fmaxf(mx, __shfl_xor(mx, 4));
                    mx = fmaxf(mx, __shfl_xor(mx, 8));
                    float mnew = fmaxf(mrow[i][r], mx);
                    float alpha = __expf(mrow[i][r] - mnew);
                    mrow[i][r] = mnew;
                    float psum = 0.f;
#pragma unroll
                    for (int j = 0; j < 4; j++) {
                        float p = __expf(s[i][j][r] - mnew);
                        s[i][j][r] = p;
                        psum += p;
                    }
                    psum += __shfl_xor(psum, 1);
                    psum += __shfl_xor(psum, 2);
                    psum += __shfl_xor(psum, 4);
                    psum += __shfl_xor(psum, 8);
                    lrow[i][r] = lrow[i][r] * alpha + psum;
#pragma unroll
                    for (int jd = 0; jd < 4; jd++) o[i][jd][r] *= alpha;
                }
            // P: C-layout regs -> LDS row-major (stride 72)
#pragma unroll
            for (int i = 0; i < 2; i++)
#pragma unroll
                for (int j = 0; j < 4; j++)
#pragma unroll
                    for (int r = 0; r < 4; r++)
                        pw[(i * 16 + quad * 4 + r) * 72 + j * 16 + l15] = f2bf(s[i][j][r]);
            // PV: A = P (A-layout read from LDS), B = Vt
#pragma unroll
            for (int kc = 0; kc < 2; kc++) {
                bf16x8 pa[2], vb[4];
#pragma unroll
                for (int i = 0; i < 2; i++)
                    pa[i] = *(const bf16x8*)(pw + (i * 16 + l15) * 72 + kc * 32 + quad * 8);
#pragma unroll
                for (int jd = 0; jd < 4; jd++)
                    vb[jd] = *(const bf16x8*)(Vt + (jd * 16 + l15) * 72 + kc * 32 + quad * 8);
#pragma unroll
                for (int i = 0; i < 2; i++)
#pragma unroll
                    for (int jd = 0; jd < 4; jd++)
                        o[i][jd] = __builtin_amdgcn_mfma_f32_16x16x32_bf16(pa[i], vb[jd], o[i][jd], 0, 0, 0);
            }
        }
    }
    // epilogue: out[row][h*64+d] = o / l
#pragma unroll
    for (int i = 0; i < 2; i++)
#pragma unroll
        for (int r = 0; r < 4; r++) {
            float inv = 1.0f / lrow[i][r];
            size_t row = (size_t)(b * 2048 + wrow + i * 16 + quad * 4 + r);
#pragma unroll
            for (int jd = 0; jd < 4; jd++)
                out[row * 1024 + h * 64 + jd * 16 + l15] = f2bf(o[i][jd][r] * inv);
        }
}

// ---------- CE per row ----------
__global__ __launch_bounds__(256) void k_ce(const float* __restrict__ logits, const int* __restrict__ targets,
                                            float* __restrict__ ce) {
    int row = blockIdx.x, tid = threadIdx.x;
    const float4* lr = (const float4*)(logits + (size_t)row * 4096);
    float4 v[4];
#pragma unroll
    for (int c = 0; c < 4; c++) v[c] = lr[tid + c * 256];
    float mx = -3e38f;
#pragma unroll
    for (int c = 0; c < 4; c++) mx = fmaxf(mx, fmaxf(fmaxf(v[c].x, v[c].y), fmaxf(v[c].z, v[c].w)));
#pragma unroll
    for (int off = 32; off; off >>= 1) mx = fmaxf(mx, __shfl_xor(mx, off));
    __shared__ float rm[4], rsum[4];
    int wid = tid >> 6, lane = tid & 63;
    if (lane == 0) rm[wid] = mx;
    __syncthreads();
    mx = fmaxf(fmaxf(rm[0], rm[1]), fmaxf(rm[2], rm[3]));
    float se = 0.f;
#pragma unroll
    for (int c = 0; c < 4; c++)
        se += __expf(v[c].x - mx) + __expf(v[c].y - mx) + __expf(v[c].z - mx) + __expf(v[c].w - mx);
#pragma unroll
    for (int off = 32; off; off >>= 1) se += __shfl_xor(se, off);
    if (lane == 0) rsum[wid] = se;
    __syncthreads();
    if (tid == 0) {
        se = rsum[0] + rsum[1] + rsum[2] + rsum[3];
        int tgt = targets[row];
        float nll = -(logits[(size_t)row * 4096 + tgt] - mx - logf(se));
        ce[row] = (tgt == 0) ? 0.f : nll;
    }
}

// ---------- final loss ----------
__global__ __launch_bounds__(256) void k_loss(const float* __restrict__ ce, const int* __restrict__ vmask,
                                              float* __restrict__ out) {
    int tid = threadIdx.x;
    int wid = tid >> 6, lane = tid & 63;
    int bad = 0;
    for (int i = tid; i < 2048; i += 256) {
        unsigned int w = ((const unsigned int*)vmask)[i];
        if (w > 1u) bad = 1;
    }
#pragma unroll
    for (int off = 32; off; off >>= 1) bad |= __shfl_xor(bad, off);
    __shared__ int sb[4];
    if (lane == 0) sb[wid] = bad;
    __syncthreads();
    bad = sb[0] | sb[1] | sb[2] | sb[3];

    float s1 = 0.f, s2 = 0.f;
    if (bad) {
        const unsigned char* mb = (const unsigned char*)vmask;
        for (int i = tid; i < 8192; i += 256) {
            float w = 1.0f + 4.0f * (mb[i] != 0);
            s1 += ce[i] * w; s2 += w;
        }
    } else {
        for (int i = tid; i < 8192; i += 256) {
            float w = 1.0f + 4.0f * (vmask[i] != 0);
            s1 += ce[i] * w; s2 += w;
        }
    }
#pragma unroll
    for (int off = 32; off; off >>= 1) { s1 += __shfl_down(s1, off); s2 += __shfl_down(s2, off); }
    __shared__ float r1[4], r2[4];
    if (lane == 0) { r1[wid] = s1; r2[wid] = s2; }
    __syncthreads();
    if (tid == 0) out[0] = (r1[0] + r1[1] + r1[2] + r1[3]) / (r2[0] + r2[1] + r2[2] + r2[3]);
}

extern "C" void kernel_launch(void* const* d_in, const int* in_sizes, int n_in,
                              void* d_out, int out_size, void* d_ws, size_t ws_size,
                              hipStream_t stream) {
    const int* input_ids = (const int*)d_in[0];
    const int* targets = (const int*)d_in[1];
    const int* vmask = (const int*)d_in[2];
    const float* token_emb = (const float*)d_in[3];
    const float* pos_emb = (const float*)d_in[4];
    const float* ln1_w = (const float*)d_in[5];
    const float* ln1_b = (const float*)d_in[6];
    const float* wqkv = (const float*)d_in[7];
    const float* bqkv = (const float*)d_in[8];
    const float* wproj = (const float*)d_in[9];
    const float* bproj = (const float*)d_in[10];
    const float* ln2_w = (const float*)d_in[11];
    const float* ln2_b = (const float*)d_in[12];
    const float* w1 = (const float*)d_in[13];
    const float* b1 = (const float*)d_in[14];
    const float* w2 = (const float*)d_in[15];
    const float* b2 = (const float*)d_in[16];
    const float* lnf_w = (const float*)d_in[17];
    const float* lnf_b = (const float*)d_in[18];

    char* p = (char*)d_ws;
    u16* embb = (u16*)p;   p += (size_t)4096 * 1024 * 2;
    u16* wqkvt = (u16*)p;  p += (size_t)8 * 3072 * 1024 * 2;
    u16* wprojt = (u16*)p; p += (size_t)8 * 1024 * 1024 * 2;
    u16* w1t = (u16*)p;    p += (size_t)8 * 4096 * 1024 * 2;
    u16* w2t = (u16*)p;    p += (size_t)8 * 1024 * 4096 * 2;
    float* xw = (float*)p; p += (size_t)8192 * 1024 * 4;
    u16* hb = (u16*)p;     p += (size_t)8192 * 1024 * 2;
    u16* qkvb = (u16*)p;   p += (size_t)8192 * 3072 * 2;
    u16* attnb = (u16*)p;  p += (size_t)8192 * 1024 * 2;
    u16* ffb = (u16*)p;    p += (size_t)8192 * 4096 * 2;
    float* cerow = (float*)p; p += 8192 * 4;

    float* logits = (float*)d_out;

    k_cvt<<<4096, 256, 0, stream>>>(token_emb, embb);
    dim3 tb(32, 8);
    k_transpose<<<dim3(96, 32, 8), tb, 0, stream>>>(wqkv, wqkvt, 1024, 3072);
    k_transpose<<<dim3(32, 32, 8), tb, 0, stream>>>(wproj, wprojt, 1024, 1024);
    k_transpose<<<dim3(128, 32, 8), tb, 0, stream>>>(w1, w1t, 1024, 4096);
    k_transpose<<<dim3(32, 128, 8), tb, 0, stream>>>(w2, w2t, 4096, 1024);

    k_embed<<<8192, 256, 0, stream>>>(input_ids, token_emb, pos_emb, xw);

    for (int l = 0; l < 8; l++) {
        k_ln<<<8192, 256, 0, stream>>>(xw, ln1_w + l * 1024, ln1_b + l * 1024, hb);
        k_gemm<true, false, false, true><<<dim3(24, 64), 256, 0, stream>>>(
            hb, wqkvt + (size_t)l * 3072 * 1024, bqkv + l * 3072, nullptr, nullptr, qkvb, 8192, 3072, 1024);
        k_attn<<<dim3(16, 64), 256, 0, stream>>>(qkvb, attnb);
        k_gemm<false, false, true, true><<<dim3(8, 64), 256, 0, stream>>>(
            attnb, wprojt + (size_t)l * 1024 * 1024, bproj + l * 1024, xw, xw, nullptr, 8192, 1024, 1024);
        k_ln<<<8192, 256, 0, stream>>>(xw, ln2_w + l * 1024, ln2_b + l * 1024, hb);
        k_gemm<true, true, false, true><<<dim3(32, 64), 256, 0, stream>>>(
            hb, w1t + (size_t)l * 4096 * 1024, b1 + l * 4096, nullptr, nullptr, ffb, 8192, 4096, 1024);
        k_gemm<false, false, true, true><<<dim3(8, 64), 256, 0, stream>>>(
            ffb, w2t + (size_t)l * 1024 * 4096, b2 + l * 1024, xw, xw, nullptr, 8192, 1024, 4096);
    }

    k_ln<<<8192, 256, 0, stream>>>(xw, lnf_w, lnf_b, hb);
    k_gemm<false, false, false, false><<<dim3(32, 64), 256, 0, stream>>>(
        hb, embb, nullptr, nullptr, logits, nullptr, 8192, 4096, 1024);

    k_ce<<<8192, 256, 0, stream>>>(logits, targets, cerow);
    k_loss<<<1, 256, 0, stream>>>(cerow, vmask, logits + (size_t)8192 * 4096);
}

// Round 2
// 5169.698 us; speedup vs baseline: 1.0457x; 1.0457x over previous
//
#include <hip/hip_runtime.h>
#include <hip/hip_bf16.h>

typedef unsigned short u16;
typedef short bf16x8 __attribute__((ext_vector_type(8)));
typedef float f32x4 __attribute__((ext_vector_type(4)));

// ---------- bf16 helpers ----------
__device__ inline float bflo(unsigned int w) { union { float f; unsigned int i; } c; c.i = w << 16; return c.f; }
__device__ inline float bfhi(unsigned int w) { union { float f; unsigned int i; } c; c.i = w & 0xffff0000u; return c.f; }
__device__ inline u16 f2bf(float f) {
    union { float f; unsigned int i; } c; c.f = f;
    unsigned int r = c.i + 0x7FFFu + ((c.i >> 16) & 1u);  // RNE
    return (u16)(r >> 16);
}

__device__ inline float wave_sum(float v) {
#pragma unroll
    for (int off = 32; off; off >>= 1) v += __shfl_down(v, off);
    return v;
}

// async global->LDS, 16B per lane. LDS dest = wave-uniform base + lane*16.
__device__ inline void gload16(const void* g, void* l) {
    __builtin_amdgcn_global_load_lds((const __attribute__((address_space(1))) void*)g,
                                     (__attribute__((address_space(3))) void*)l, 16, 0, 0);
}

// ---------- convert token_emb -> bf16 (V*D = 4096*1024) ----------
__global__ __launch_bounds__(256) void k_cvt(const float* __restrict__ in, u16* __restrict__ out) {
    int i = blockIdx.x * 256 + threadIdx.x;  // over n/4
    float4 v = ((const float4*)in)[i];
    ushort4 o;
    o.x = f2bf(v.x); o.y = f2bf(v.y); o.z = f2bf(v.z); o.w = f2bf(v.w);
    ((ushort4*)out)[i] = o;
}

// ---------- transpose + convert: in fp32 (R,C) -> out bf16 (C,R), z = layer ----------
__global__ __launch_bounds__(256) void k_transpose(const float* __restrict__ in, u16* __restrict__ out, int R, int C) {
    __shared__ float tile[32][33];
    const float* inL = in + (size_t)blockIdx.z * R * C;
    u16* outL = out + (size_t)blockIdx.z * R * C;
    int cb = blockIdx.x * 32, rb = blockIdx.y * 32;
    int tx = threadIdx.x, ty = threadIdx.y;  // (32,8)
#pragma unroll
    for (int i = 0; i < 32; i += 8)
        tile[ty + i][tx] = inL[(size_t)(rb + ty + i) * C + cb + tx];
    __syncthreads();
#pragma unroll
    for (int i = 0; i < 32; i += 8)
        outL[(size_t)(cb + ty + i) * R + rb + tx] = f2bf(tile[tx][ty + i]);
}

// ---------- embedding ----------
__global__ __launch_bounds__(256) void k_embed(const int* __restrict__ ids, const float* __restrict__ emb,
                                               const float* __restrict__ pos, float* __restrict__ x) {
    int i = blockIdx.x * 256 + threadIdx.x;
    int m = i >> 8;
    int d4 = i & 255;
    int t = m & 2047;
    int id = ids[m];
    float4 e = ((const float4*)(emb + (size_t)id * 1024))[d4];
    float4 p = ((const float4*)(pos + (size_t)t * 1024))[d4];
    float4 r; r.x = e.x + p.x; r.y = e.y + p.y; r.z = e.z + p.z; r.w = e.w + p.w;
    ((float4*)(x + (size_t)m * 1024))[d4] = r;
}

// ---------- layernorm: fp32 in (row of 1024) -> bf16 out ----------
__global__ __launch_bounds__(256) void k_ln(const float* __restrict__ in, const float* __restrict__ w,
                                            const float* __restrict__ b, u16* __restrict__ out) {
    int row = blockIdx.x, tid = threadIdx.x;
    float4 v = ((const float4*)(in + (size_t)row * 1024))[tid];
    float s = v.x + v.y + v.z + v.w;
    float ss = v.x * v.x + v.y * v.y + v.z * v.z + v.w * v.w;
    s = wave_sum(s); ss = wave_sum(ss);
    __shared__ float rs[4], rss[4];
    int wid = tid >> 6, lane = tid & 63;
    if (lane == 0) { rs[wid] = s; rss[wid] = ss; }
    __syncthreads();
    s = rs[0] + rs[1] + rs[2] + rs[3];
    ss = rss[0] + rss[1] + rss[2] + rss[3];
    float mu = s * (1.0f / 1024.0f);
    float var = ss * (1.0f / 1024.0f) - mu * mu;
    float inv = rsqrtf(var + 1e-5f);
    float4 wv = ((const float4*)w)[tid], bv = ((const float4*)b)[tid];
    ushort4 o;
    o.x = f2bf((v.x - mu) * inv * wv.x + bv.x);
    o.y = f2bf((v.y - mu) * inv * wv.y + bv.y);
    o.z = f2bf((v.z - mu) * inv * wv.z + bv.z);
    o.w = f2bf((v.w - mu) * inv * wv.w + bv.w);
    *(ushort4*)(out + (size_t)row * 1024 + tid * 4) = o;
}

// ---------- MFMA GEMM: C(M,N) = A(M,K) @ Bt(N,K)^T [+bias][gelu][+res] ----------
// 2-phase double-buffered staging (T3-minimum recipe): while MFMAs consume buf[cur],
// global_load_lds prefetches tile t+1 into buf[cur^1]; single __syncthreads per
// K-step (its vmcnt/lgkm drain covers both the prefetch and the ds_reads).
// LDS layout linear in tid: dest = wave-uniform base + lane*16B.
template <bool OUT_BF16, bool GELU, bool RES, bool BIAS>
__global__ __launch_bounds__(256, 2) void k_gemm(const u16* __restrict__ A, const u16* __restrict__ Bt,
                                                 const float* __restrict__ bias, const float* __restrict__ res,
                                                 float* __restrict__ outF, u16* __restrict__ outB,
                                                 int M, int N, int K) {
    __shared__ __align__(16) u16 ldsA[2][128 * 32];
    __shared__ __align__(16) u16 ldsB[2][128 * 32];
    int tid = threadIdx.x;
    int wave = tid >> 6, lane = tid & 63;
    int quad = lane >> 4, l15 = lane & 15;
    int m0 = blockIdx.y * 128, n0 = blockIdx.x * 128;
    int wm = (wave >> 1) * 64, wn = (wave & 1) * 64;

    f32x4 acc[4][4];
#pragma unroll
    for (int i = 0; i < 4; i++)
#pragma unroll
        for (int j = 0; j < 4; j++) acc[i][j] = (f32x4){0.f, 0.f, 0.f, 0.f};

    int r0 = tid >> 2, c0 = (tid & 3) * 8;
    const size_t half = (size_t)64 * K;
    const u16* pa0 = A + (size_t)(m0 + r0) * K + c0;
    const u16* pb0 = Bt + (size_t)(n0 + r0) * K + c0;
    const int woff = (tid & 0xC0) * 8;  // wave base in u16 (wave*512 u16 = wave*1KB)

#define STAGE(bi, k0)                              \
    {                                              \
        u16* la_ = ldsA[bi] + woff;                \
        u16* lb_ = ldsB[bi] + woff;                \
        gload16(pa0 + (k0), la_);                  \
        gload16(pa0 + half + (k0), la_ + 2048);    \
        gload16(pb0 + (k0), lb_);                  \
        gload16(pb0 + half + (k0), lb_ + 2048);    \
    }

    STAGE(0, 0);
    __syncthreads();  // drains vmcnt: tile 0 resident

    const int nt = K >> 5;
    int cur = 0;
    for (int t = 0; t < nt; t++) {
        if (t + 1 < nt) STAGE(cur ^ 1, (t + 1) * 32);  // prefetch next tile (async)
        const u16* ca = ldsA[cur];
        const u16* cb = ldsB[cur];
        bf16x8 af[4], bfr[4];
#pragma unroll
        for (int i = 0; i < 4; i++) af[i] = *(const bf16x8*)(ca + (wm + i * 16 + l15) * 32 + quad * 8);
#pragma unroll
        for (int j = 0; j < 4; j++) bfr[j] = *(const bf16x8*)(cb + (wn + j * 16 + l15) * 32 + quad * 8);
#pragma unroll
        for (int i = 0; i < 4; i++)
#pragma unroll
            for (int j = 0; j < 4; j++)
                acc[i][j] = __builtin_amdgcn_mfma_f32_16x16x32_bf16(af[i], bfr[j], acc[i][j], 0, 0, 0);
        __syncthreads();  // prefetch landed (vmcnt drain) + all reads of buf[cur] done
        cur ^= 1;
    }
#undef STAGE

#pragma unroll
    for (int j = 0; j < 4; j++) {
        int col = n0 + wn + j * 16 + l15;
        float bj = BIAS ? bias[col] : 0.f;
#pragma unroll
        for (int i = 0; i < 4; i++) {
#pragma unroll
            for (int r = 0; r < 4; r++) {
                int row = m0 + wm + i * 16 + quad * 4 + r;
                float v = acc[i][j][r] + bj;
                if (GELU) v = 0.5f * v * (1.0f + erff(v * 0.70710678f));
                if (RES) v += res[(size_t)row * N + col];
                if (OUT_BF16) outB[(size_t)row * N + col] = f2bf(v);
                else outF[(size_t)row * N + col] = v;
            }
        }
    }
}

// ---------- MFMA flash attention ----------
// qkv bf16 (B*T, 3072): q at h*64, k at 1024+h*64, v at 2048+h*64. out bf16 (B*T, 1024).
// Block: 256 thr = 4 waves; handles (b,h) x 128 Q rows (wave w -> 32 rows).
// K-tiles of 64. LDS stride 72 (16B-aligned rows, no superbank alias).
// launch_bounds(256,2): (256,4) pinned VGPR=64 -> scratch spills (FETCH +82MB, dur +8%). Reverted.
__global__ __launch_bounds__(256, 2) void k_attn(const u16* __restrict__ qkv, u16* __restrict__ out) {
    const int b = blockIdx.y >> 4, h = blockIdx.y & 15;
    const int qt = gridDim.x - 1 - blockIdx.x;  // heavy tiles first
    const int q0 = qt * 128;
    const int tid = threadIdx.x;
    const int wave = tid >> 6, lane = tid & 63;
    const int quad = lane >> 4, l15 = lane & 15;
    const int wrow = q0 + wave * 32;

    __shared__ __align__(16) u16 Klds[64 * 72];
    __shared__ __align__(16) u16 Vt[64 * 72];        // Vt[d][krow]
    __shared__ __align__(16) u16 Plds[4][32 * 72];   // wave-private

    const u16* base = qkv + (size_t)b * 2048 * 3072 + h * 64;

    // Q fragments (A-layout): rows wrow+i*16+l15, k = kc*32+quad*8
    bf16x8 qf[2][2];
#pragma unroll
    for (int i = 0; i < 2; i++)
#pragma unroll
        for (int kc = 0; kc < 2; kc++)
            qf[i][kc] = *(const bf16x8*)(base + (size_t)(wrow + i * 16 + l15) * 3072 + kc * 32 + quad * 8);

    f32x4 o[2][4];
#pragma unroll
    for (int i = 0; i < 2; i++)
#pragma unroll
        for (int jd = 0; jd < 4; jd++) o[i][jd] = (f32x4){0.f, 0.f, 0.f, 0.f};
    float mrow[2][4], lrow[2][4];
#pragma unroll
    for (int i = 0; i < 2; i++)
#pragma unroll
        for (int r = 0; r < 4; r++) { mrow[i][r] = -3e38f; lrow[i][r] = 0.f; }

    // staging assignments
    const int kk_ = tid >> 2, kc0 = (tid & 3) * 16;  // K: row kk_, cols kc0..kc0+15
    const int vk = tid & 63, vc = (tid >> 6) * 16;   // V: row vk, cols vc..vc+15 (transposed write)

    const int ktiles = 2 * (qt + 1);
    for (int t = 0; t < ktiles; t++) {
        const int kt = t * 64;
        __syncthreads();
        {
            const u16* kp = base + 1024 + (size_t)(kt + kk_) * 3072 + kc0;
            uint4 a = *(const uint4*)kp;
            uint4 c = *(const uint4*)(kp + 8);
            *(uint4*)(Klds + kk_ * 72 + kc0) = a;
            *(uint4*)(Klds + kk_ * 72 + kc0 + 8) = c;
            const u16* vp = base + 2048 + (size_t)(kt + vk) * 3072 + vc;
            uint4 v0 = *(const uint4*)vp;
            uint4 v1 = *(const uint4*)(vp + 8);
            u16 tmp[16];
            *(uint4*)tmp = v0; *(uint4*)(tmp + 8) = v1;
#pragma unroll
            for (int e = 0; e < 16; e++) Vt[(vc + e) * 72 + vk] = tmp[e];
        }
        __syncthreads();

        if (kt <= wrow + 31) {
            // S = Q @ K^T
            f32x4 s[2][4];
#pragma unroll
            for (int i = 0; i < 2; i++)
#pragma unroll
                for (int j = 0; j < 4; j++) s[i][j] = (f32x4){0.f, 0.f, 0.f, 0.f};
#pragma unroll
            for (int kc = 0; kc < 2; kc++) {
                bf16x8 bf[4];
#pragma unroll
                for (int j = 0; j < 4; j++)
                    bf[j] = *(const bf16x8*)(Klds + (j * 16 + l15) * 72 + kc * 32 + quad * 8);
#pragma unroll
                for (int i = 0; i < 2; i++)
#pragma unroll
                    for (int j = 0; j < 4; j++)
                        s[i][j] = __builtin_amdgcn_mfma_f32_16x16x32_bf16(qf[i][kc], bf[j], s[i][j], 0, 0, 0);
            }
            const bool partial = (kt + 63 > wrow);  // tile crosses the diagonal for this wave
#pragma unroll
            for (int i = 0; i < 2; i++)
#pragma unroll
                for (int j = 0; j < 4; j++)
#pragma unroll
                    for (int r = 0; r < 4; r++) {
                        float v = s[i][j][r] * 0.125f;
                        if (partial) {
                            int row = wrow + i * 16 + quad * 4 + r;
                            int col = kt + j * 16 + l15;
                            if (col > row) v = -3e30f;
                        }
                        s[i][j][r] = v;
                    }
            // online softmax per row (i,r); row constant across the 16-lane col group
            u16* pw = Plds[wave];
#pragma unroll
            for (int i = 0; i < 2; i++)
#pragma unroll
                for (int r = 0; r < 4; r++) {
                    float mx = fmaxf(fmaxf(s[i][0][r], s[i][1][r]), fmaxf(s[i][2][r], s[i][3][r]));
                    mx = fmaxf(mx, __shfl_xor(mx, 1));
                    mx = fmaxf(mx, __shfl_xor(mx, 2));
                    mx = fmaxf(mx, __shfl_xor(mx, 4));
                    mx = fmaxf(mx, __shfl_xor(mx, 8));
                    float mnew = fmaxf(mrow[i][r], mx);
                    float alpha = __expf(mrow[i][r] - mnew);
                    mrow[i][r] = mnew;
                    float psum = 0.f;
#pragma unroll
                    for (int j = 0; j < 4; j++) {
                        float p = __expf(s[i][j][r] - mnew);
                        s[i][j][r] = p;
                        psum += p;
                    }
                    psum += __shfl_xor(psum, 1);
                    psum += __shfl_xor(psum, 2);
                    psum += __shfl_xor(psum, 4);
                    psum += __shfl_xor(psum, 8);
                    lrow[i][r] = lrow[i][r] * alpha + psum;
#pragma unroll
                    for (int jd = 0; jd < 4; jd++) o[i][jd][r] *= alpha;
                }
            // P: C-layout regs -> LDS row-major (stride 72)
#pragma unroll
            for (int i = 0; i < 2; i++)
#pragma unroll
                for (int j = 0; j < 4; j++)
#pragma unroll
                    for (int r = 0; r < 4; r++)
                        pw[(i * 16 + quad * 4 + r) * 72 + j * 16 + l15] = f2bf(s[i][j][r]);
            // PV: A = P (A-layout read from LDS), B = Vt
#pragma unroll
            for (int kc = 0; kc < 2; kc++) {
                bf16x8 pa[2], vb[4];
#pragma unroll
                for (int i = 0; i < 2; i++)
                    pa[i] = *(const bf16x8*)(pw + (i * 16 + l15) * 72 + kc * 32 + quad * 8);
#pragma unroll
                for (int jd = 0; jd < 4; jd++)
                    vb[jd] = *(const bf16x8*)(Vt + (jd * 16 + l15) * 72 + kc * 32 + quad * 8);
#pragma unroll
                for (int i = 0; i < 2; i++)
#pragma unroll
                    for (int jd = 0; jd < 4; jd++)
                        o[i][jd] = __builtin_amdgcn_mfma_f32_16x16x32_bf16(pa[i], vb[jd], o[i][jd], 0, 0, 0);
            }
        }
    }
    // epilogue: out[row][h*64+d] = o / l
#pragma unroll
    for (int i = 0; i < 2; i++)
#pragma unroll
        for (int r = 0; r < 4; r++) {
            float inv = 1.0f / lrow[i][r];
            size_t row = (size_t)(b * 2048 + wrow + i * 16 + quad * 4 + r);
#pragma unroll
            for (int jd = 0; jd < 4; jd++)
                out[row * 1024 + h * 64 + jd * 16 + l15] = f2bf(o[i][jd][r] * inv);
        }
}

// ---------- CE per row ----------
__global__ __launch_bounds__(256) void k_ce(const float* __restrict__ logits, const int* __restrict__ targets,
                                            float* __restrict__ ce) {
    int row = blockIdx.x, tid = threadIdx.x;
    const float4* lr = (const float4*)(logits + (size_t)row * 4096);
    float4 v[4];
#pragma unroll
    for (int c = 0; c < 4; c++) v[c] = lr[tid + c * 256];
    float mx = -3e38f;
#pragma unroll
    for (int c = 0; c < 4; c++) mx = fmaxf(mx, fmaxf(fmaxf(v[c].x, v[c].y), fmaxf(v[c].z, v[c].w)));
#pragma unroll
    for (int off = 32; off; off >>= 1) mx = fmaxf(mx, __shfl_xor(mx, off));
    __shared__ float rm[4], rsum[4];
    int wid = tid >> 6, lane = tid & 63;
    if (lane == 0) rm[wid] = mx;
    __syncthreads();
    mx = fmaxf(fmaxf(rm[0], rm[1]), fmaxf(rm[2], rm[3]));
    float se = 0.f;
#pragma unroll
    for (int c = 0; c < 4; c++)
        se += __expf(v[c].x - mx) + __expf(v[c].y - mx) + __expf(v[c].z - mx) + __expf(v[c].w - mx);
#pragma unroll
    for (int off = 32; off; off >>= 1) se += __shfl_xor(se, off);
    if (lane == 0) rsum[wid] = se;
    __syncthreads();
    if (tid == 0) {
        se = rsum[0] + rsum[1] + rsum[2] + rsum[3];
        int tgt = targets[row];
        float nll = -(logits[(size_t)row * 4096 + tgt] - mx - logf(se));
        ce[row] = (tgt == 0) ? 0.f : nll;
    }
}

// ---------- final loss ----------
__global__ __launch_bounds__(256) void k_loss(const float* __restrict__ ce, const int* __restrict__ vmask,
                                              float* __restrict__ out) {
    int tid = threadIdx.x;
    int wid = tid >> 6, lane = tid & 63;
    int bad = 0;
    for (int i = tid; i < 2048; i += 256) {
        unsigned int w = ((const unsigned int*)vmask)[i];
        if (w > 1u) bad = 1;
    }
#pragma unroll
    for (int off = 32; off; off >>= 1) bad |= __shfl_xor(bad, off);
    __shared__ int sb[4];
    if (lane == 0) sb[wid] = bad;
    __syncthreads();
    bad = sb[0] | sb[1] | sb[2] | sb[3];

    float s1 = 0.f, s2 = 0.f;
    if (bad) {
        const unsigned char* mb = (const unsigned char*)vmask;
        for (int i = tid; i < 8192; i += 256) {
            float w = 1.0f + 4.0f * (mb[i] != 0);
            s1 += ce[i] * w; s2 += w;
        }
    } else {
        for (int i = tid; i < 8192; i += 256) {
            float w = 1.0f + 4.0f * (vmask[i] != 0);
            s1 += ce[i] * w; s2 += w;
        }
    }
#pragma unroll
    for (int off = 32; off; off >>= 1) { s1 += __shfl_down(s1, off); s2 += __shfl_down(s2, off); }
    __shared__ float r1[4], r2[4];
    if (lane == 0) { r1[wid] = s1; r2[wid] = s2; }
    __syncthreads();
    if (tid == 0) out[0] = (r1[0] + r1[1] + r1[2] + r1[3]) / (r2[0] + r2[1] + r2[2] + r2[3]);
}

extern "C" void kernel_launch(void* const* d_in, const int* in_sizes, int n_in,
                              void* d_out, int out_size, void* d_ws, size_t ws_size,
                              hipStream_t stream) {
    const int* input_ids = (const int*)d_in[0];
    const int* targets = (const int*)d_in[1];
    const int* vmask = (const int*)d_in[2];
    const float* token_emb = (const float*)d_in[3];
    const float* pos_emb = (const float*)d_in[4];
    const float* ln1_w = (const float*)d_in[5];
    const float* ln1_b = (const float*)d_in[6];
    const float* wqkv = (const float*)d_in[7];
    const float* bqkv = (const float*)d_in[8];
    const float* wproj = (const float*)d_in[9];
    const float* bproj = (const float*)d_in[10];
    const float* ln2_w = (const float*)d_in[11];
    const float* ln2_b = (const float*)d_in[12];
    const float* w1 = (const float*)d_in[13];
    const float* b1 = (const float*)d_in[14];
    const float* w2 = (const float*)d_in[15];
    const float* b2 = (const float*)d_in[16];
    const float* lnf_w = (const float*)d_in[17];
    const float* lnf_b = (const float*)d_in[18];

    char* p = (char*)d_ws;
    u16* embb = (u16*)p;   p += (size_t)4096 * 1024 * 2;
    u16* wqkvt = (u16*)p;  p += (size_t)8 * 3072 * 1024 * 2;
    u16* wprojt = (u16*)p; p += (size_t)8 * 1024 * 1024 * 2;
    u16* w1t = (u16*)p;    p += (size_t)8 * 4096 * 1024 * 2;
    u16* w2t = (u16*)p;    p += (size_t)8 * 1024 * 4096 * 2;
    float* xw = (float*)p; p += (size_t)8192 * 1024 * 4;
    u16* hb = (u16*)p;     p += (size_t)8192 * 1024 * 2;
    u16* qkvb = (u16*)p;   p += (size_t)8192 * 3072 * 2;
    u16* attnb = (u16*)p;  p += (size_t)8192 * 1024 * 2;
    u16* ffb = (u16*)p;    p += (size_t)8192 * 4096 * 2;
    float* cerow = (float*)p; p += 8192 * 4;

    float* logits = (float*)d_out;

    k_cvt<<<4096, 256, 0, stream>>>(token_emb, embb);
    dim3 tb(32, 8);
    k_transpose<<<dim3(96, 32, 8), tb, 0, stream>>>(wqkv, wqkvt, 1024, 3072);
    k_transpose<<<dim3(32, 32, 8), tb, 0, stream>>>(wproj, wprojt, 1024, 1024);
    k_transpose<<<dim3(128, 32, 8), tb, 0, stream>>>(w1, w1t, 1024, 4096);
    k_transpose<<<dim3(32, 128, 8), tb, 0, stream>>>(w2, w2t, 4096, 1024);

    k_embed<<<8192, 256, 0, stream>>>(input_ids, token_emb, pos_emb, xw);

    for (int l = 0; l < 8; l++) {
        k_ln<<<8192, 256, 0, stream>>>(xw, ln1_w + l * 1024, ln1_b + l * 1024, hb);
        k_gemm<true, false, false, true><<<dim3(24, 64), 256, 0, stream>>>(
            hb, wqkvt + (size_t)l * 3072 * 1024, bqkv + l * 3072, nullptr, nullptr, qkvb, 8192, 3072, 1024);
        k_attn<<<dim3(16, 64), 256, 0, stream>>>(qkvb, attnb);
        k_gemm<false, false, true, true><<<dim3(8, 64), 256, 0, stream>>>(
            attnb, wprojt + (size_t)l * 1024 * 1024, bproj + l * 1024, xw, xw, nullptr, 8192, 1024, 1024);
        k_ln<<<8192, 256, 0, stream>>>(xw, ln2_w + l * 1024, ln2_b + l * 1024, hb);
        k_gemm<true, true, false, true><<<dim3(32, 64), 256, 0, stream>>>(
            hb, w1t + (size_t)l * 4096 * 1024, b1 + l * 4096, nullptr, nullptr, ffb, 8192, 4096, 1024);
        k_gemm<false, false, true, true><<<dim3(8, 64), 256, 0, stream>>>(
            ffb, w2t + (size_t)l * 1024 * 4096, b2 + l * 1024, xw, xw, nullptr, 8192, 1024, 4096);
    }

    k_ln<<<8192, 256, 0, stream>>>(xw, lnf_w, lnf_b, hb);
    k_gemm<false, false, false, false><<<dim3(32, 64), 256, 0, stream>>>(
        hb, embb, nullptr, nullptr, logits, nullptr, 8192, 4096, 1024);

    k_ce<<<8192, 256, 0, stream>>>(logits, targets, cerow);
    k_loss<<<1, 256, 0, stream>>>(cerow, vmask, logits + (size_t)8192 * 4096);
}

// Round 3
// 4982.944 us; speedup vs baseline: 1.0849x; 1.0375x over previous
//
#include <hip/hip_runtime.h>
#include <hip/hip_bf16.h>

typedef unsigned short u16;
typedef short bf16x8 __attribute__((ext_vector_type(8)));
typedef float f32x4 __attribute__((ext_vector_type(4)));

// ---------- bf16 helpers ----------
__device__ inline u16 f2bf(float f) {
    union { float f; unsigned int i; } c; c.f = f;
    unsigned int r = c.i + 0x7FFFu + ((c.i >> 16) & 1u);  // RNE
    return (u16)(r >> 16);
}

__device__ inline float wave_sum(float v) {
#pragma unroll
    for (int off = 32; off; off >>= 1) v += __shfl_down(v, off);
    return v;
}

// async global->LDS, 16B per lane. LDS dest = wave-uniform base + lane*16.
__device__ inline void gload16(const void* g, void* l) {
    __builtin_amdgcn_global_load_lds((const __attribute__((address_space(1))) void*)g,
                                     (__attribute__((address_space(3))) void*)l, 16, 0, 0);
}

// ---------- convert token_emb -> bf16 (V*D = 4096*1024) ----------
__global__ __launch_bounds__(256) void k_cvt(const float* __restrict__ in, u16* __restrict__ out) {
    int i = blockIdx.x * 256 + threadIdx.x;  // over n/4
    float4 v = ((const float4*)in)[i];
    ushort4 o;
    o.x = f2bf(v.x); o.y = f2bf(v.y); o.z = f2bf(v.z); o.w = f2bf(v.w);
    ((ushort4*)out)[i] = o;
}

// ---------- transpose + convert: in fp32 (R,C) -> out bf16 (C,R), z = layer ----------
__global__ __launch_bounds__(256) void k_transpose(const float* __restrict__ in, u16* __restrict__ out, int R, int C) {
    __shared__ float tile[32][33];
    const float* inL = in + (size_t)blockIdx.z * R * C;
    u16* outL = out + (size_t)blockIdx.z * R * C;
    int cb = blockIdx.x * 32, rb = blockIdx.y * 32;
    int tx = threadIdx.x, ty = threadIdx.y;  // (32,8)
#pragma unroll
    for (int i = 0; i < 32; i += 8)
        tile[ty + i][tx] = inL[(size_t)(rb + ty + i) * C + cb + tx];
    __syncthreads();
#pragma unroll
    for (int i = 0; i < 32; i += 8)
        outL[(size_t)(cb + ty + i) * R + rb + tx] = f2bf(tile[tx][ty + i]);
}

// ---------- embedding ----------
__global__ __launch_bounds__(256) void k_embed(const int* __restrict__ ids, const float* __restrict__ emb,
                                               const float* __restrict__ pos, float* __restrict__ x) {
    int i = blockIdx.x * 256 + threadIdx.x;
    int m = i >> 8;
    int d4 = i & 255;
    int t = m & 2047;
    int id = ids[m];
    float4 e = ((const float4*)(emb + (size_t)id * 1024))[d4];
    float4 p = ((const float4*)(pos + (size_t)t * 1024))[d4];
    float4 r; r.x = e.x + p.x; r.y = e.y + p.y; r.z = e.z + p.z; r.w = e.w + p.w;
    ((float4*)(x + (size_t)m * 1024))[d4] = r;
}

// ---------- layernorm: fp32 in (row of 1024) -> bf16 out ----------
__global__ __launch_bounds__(256) void k_ln(const float* __restrict__ in, const float* __restrict__ w,
                                            const float* __restrict__ b, u16* __restrict__ out) {
    int row = blockIdx.x, tid = threadIdx.x;
    float4 v = ((const float4*)(in + (size_t)row * 1024))[tid];
    float s = v.x + v.y + v.z + v.w;
    float ss = v.x * v.x + v.y * v.y + v.z * v.z + v.w * v.w;
    s = wave_sum(s); ss = wave_sum(ss);
    __shared__ float rs[4], rss[4];
    int wid = tid >> 6, lane = tid & 63;
    if (lane == 0) { rs[wid] = s; rss[wid] = ss; }
    __syncthreads();
    s = rs[0] + rs[1] + rs[2] + rs[3];
    ss = rss[0] + rss[1] + rss[2] + rss[3];
    float mu = s * (1.0f / 1024.0f);
    float var = ss * (1.0f / 1024.0f) - mu * mu;
    float inv = rsqrtf(var + 1e-5f);
    float4 wv = ((const float4*)w)[tid], bv = ((const float4*)b)[tid];
    ushort4 o;
    o.x = f2bf((v.x - mu) * inv * wv.x + bv.x);
    o.y = f2bf((v.y - mu) * inv * wv.y + bv.y);
    o.z = f2bf((v.z - mu) * inv * wv.z + bv.z);
    o.w = f2bf((v.w - mu) * inv * wv.w + bv.w);
    *(ushort4*)(out + (size_t)row * 1024 + tid * 4) = o;
}

// ---------- 128x128 MFMA GEMM (2-phase dbuf) — used for N=1024 GEMMs ----------
template <bool OUT_BF16, bool GELU, bool RES, bool BIAS>
__global__ __launch_bounds__(256, 2) void k_gemm(const u16* __restrict__ A, const u16* __restrict__ Bt,
                                                 const float* __restrict__ bias, const float* __restrict__ res,
                                                 float* __restrict__ outF, u16* __restrict__ outB,
                                                 int M, int N, int K) {
    __shared__ __align__(16) u16 ldsA[2][128 * 32];
    __shared__ __align__(16) u16 ldsB[2][128 * 32];
    int tid = threadIdx.x;
    int wave = tid >> 6, lane = tid & 63;
    int quad = lane >> 4, l15 = lane & 15;
    int m0 = blockIdx.y * 128, n0 = blockIdx.x * 128;
    int wm = (wave >> 1) * 64, wn = (wave & 1) * 64;

    f32x4 acc[4][4];
#pragma unroll
    for (int i = 0; i < 4; i++)
#pragma unroll
        for (int j = 0; j < 4; j++) acc[i][j] = (f32x4){0.f, 0.f, 0.f, 0.f};

    int r0 = tid >> 2, c0 = (tid & 3) * 8;
    const size_t half = (size_t)64 * K;
    const u16* pa0 = A + (size_t)(m0 + r0) * K + c0;
    const u16* pb0 = Bt + (size_t)(n0 + r0) * K + c0;
    const int woff = (tid & 0xC0) * 8;

#define STAGE(bi, k0)                              \
    {                                              \
        u16* la_ = ldsA[bi] + woff;                \
        u16* lb_ = ldsB[bi] + woff;                \
        gload16(pa0 + (k0), la_);                  \
        gload16(pa0 + half + (k0), la_ + 2048);    \
        gload16(pb0 + (k0), lb_);                  \
        gload16(pb0 + half + (k0), lb_ + 2048);    \
    }

    STAGE(0, 0);
    __syncthreads();

    const int nt = K >> 5;
    int cur = 0;
    for (int t = 0; t < nt; t++) {
        if (t + 1 < nt) STAGE(cur ^ 1, (t + 1) * 32);
        const u16* ca = ldsA[cur];
        const u16* cb = ldsB[cur];
        bf16x8 af[4], bfr[4];
#pragma unroll
        for (int i = 0; i < 4; i++) af[i] = *(const bf16x8*)(ca + (wm + i * 16 + l15) * 32 + quad * 8);
#pragma unroll
        for (int j = 0; j < 4; j++) bfr[j] = *(const bf16x8*)(cb + (wn + j * 16 + l15) * 32 + quad * 8);
#pragma unroll
        for (int i = 0; i < 4; i++)
#pragma unroll
            for (int j = 0; j < 4; j++)
                acc[i][j] = __builtin_amdgcn_mfma_f32_16x16x32_bf16(af[i], bfr[j], acc[i][j], 0, 0, 0);
        __syncthreads();
        cur ^= 1;
    }
#undef STAGE

#pragma unroll
    for (int j = 0; j < 4; j++) {
        int col = n0 + wn + j * 16 + l15;
        float bj = BIAS ? bias[col] : 0.f;
#pragma unroll
        for (int i = 0; i < 4; i++) {
#pragma unroll
            for (int r = 0; r < 4; r++) {
                int row = m0 + wm + i * 16 + quad * 4 + r;
                float v = acc[i][j][r] + bj;
                if (GELU) v = 0.5f * v * (1.0f + erff(v * 0.70710678f));
                if (RES) v += res[(size_t)row * N + col];
                if (OUT_BF16) outB[(size_t)row * N + col] = f2bf(v);
                else outF[(size_t)row * N + col] = v;
            }
        }
    }
}

// ---------- 256x256 8-phase MFMA GEMM (T2 swizzle + T3/T4 counted vmcnt + T5 setprio) ----------
// 512 thr / 8 waves (2M x 4N), BK=64, per-wave 128x64 out, 64 MFMA per K-tile in 4 phases of 16.
// LDS: 2 x 32KB per matrix (128KB), linear gload_lds dest; swizzle via pre-swizzled GLOBAL source
// + swizzled ds_read (rule #21): byte col cb ^= (row&7)<<4 within the 128B row.
// Half-tile issue schedule: tile T's halves {A0,A1,B0,B1} issued at (T-2).P4, (T-1).P1..P3.
// Wait s_waitcnt vmcnt(2) once per K-tile at P4 (2 ops = the one half-tile issued this phase);
// vmcnt(0) only at the t=NT-2 drain. Raw s_barrier (NOT __syncthreads: that drains vmcnt).
// Requires: M%256==0, N%256==0, K%64==0, K>=192.
template <bool OUT_BF16, bool GELU, bool BIAS>
__global__ __launch_bounds__(512, 2) void k_gemm256(const u16* __restrict__ A, const u16* __restrict__ Bt,
                                                    const float* __restrict__ bias,
                                                    float* __restrict__ outF, u16* __restrict__ outB,
                                                    int M, int N, int K) {
    __shared__ __align__(16) u16 As[2][256 * 64];
    __shared__ __align__(16) u16 Bs[2][256 * 64];
    const int tid = threadIdx.x;
    const int lane = tid & 63;
    const int quad = lane >> 4, l15 = lane & 15;
    const int m0 = blockIdx.y * 256, n0 = blockIdx.x * 256;
    const int wm = ((tid >> 6) >> 2) * 128;   // 0 | 128
    const int wn = ((tid >> 6) & 3) * 64;     // 0 | 64 | 128 | 192
    const int NT = K >> 6;

    f32x4 acc[8][4];
#pragma unroll
    for (int i = 0; i < 8; i++)
#pragma unroll
        for (int j = 0; j < 4; j++) acc[i][j] = (f32x4){0.f, 0.f, 0.f, 0.f};

    // staging: thread -> (row rS in 64-row issue block, 16B chunk cS), source col pre-swizzled
    const int rS = tid >> 3;
    const int cSwz = ((tid & 7) * 16) ^ ((rS & 7) << 4);  // issue-block-invariant (64%8==0)
    const u16* gA = A + (size_t)(m0 + rS) * K + (cSwz >> 1);
    const u16* gB = Bt + (size_t)(n0 + rS) * K + (cSwz >> 1);

    // issue one half-tile (2 x gload16) of tile t: j=0,1 -> A half j; j=2,3 -> B half j-2
    auto issue_half = [&](int t, int j) {
        if (t >= NT) return;
        const int bf = t & 1;
        if (j <= 1) {
            const u16* src = gA + (size_t)(j * 128) * K + (size_t)t * 64;
            u16* dst = &As[bf][j * 8192 + tid * 8];
            gload16(src, dst);
            gload16(src + (size_t)64 * K, dst + 4096);
        } else {
            const int h = j - 2;
            const u16* src = gB + (size_t)(h * 128) * K + (size_t)t * 64;
            u16* dst = &Bs[bf][h * 8192 + tid * 8];
            gload16(src, dst);
            gload16(src + (size_t)64 * K, dst + 4096);
        }
    };
    auto ldA = [&](int bf, int mi, int ks) {
        int r = wm + mi * 16 + l15;
        int cb = (ks * 64 + quad * 16) ^ ((r & 7) << 4);
        return *(const bf16x8*)((const char*)&As[bf][0] + (size_t)r * 128 + cb);
    };
    auto ldB = [&](int bf, int nj, int ks) {
        int r = wn + nj * 16 + l15;
        int cb = (ks * 64 + quad * 16) ^ ((r & 7) << 4);
        return *(const bf16x8*)((const char*)&Bs[bf][0] + (size_t)r * 128 + cb);
    };

    // prologue: tile0 fully + tile1.H0; tile0 landed when <=2 ops outstanding
    issue_half(0, 0); issue_half(0, 1); issue_half(0, 2); issue_half(0, 3);
    issue_half(1, 0);
    asm volatile("s_waitcnt vmcnt(2)" ::: "memory");
    __builtin_amdgcn_s_barrier();

    for (int t = 0; t < NT; t++) {
        const int bf = t & 1;
        bf16x8 a0[4], a1[4], b0[4], b1[4];
        // ---- P1: A(0..3,k0), B(k0); MFMA quadrant (M-half0, k0)
#pragma unroll
        for (int mi = 0; mi < 4; mi++) a0[mi] = ldA(bf, mi, 0);
#pragma unroll
        for (int nj = 0; nj < 4; nj++) b0[nj] = ldB(bf, nj, 0);
        issue_half(t + 1, 1);
        __builtin_amdgcn_s_barrier();
        __builtin_amdgcn_s_setprio(1);
#pragma unroll
        for (int mi = 0; mi < 4; mi++)
#pragma unroll
            for (int nj = 0; nj < 4; nj++)
                acc[mi][nj] = __builtin_amdgcn_mfma_f32_16x16x32_bf16(a0[mi], b0[nj], acc[mi][nj], 0, 0, 0);
        __builtin_amdgcn_s_setprio(0);
        __builtin_amdgcn_s_barrier();
        // ---- P2: A(0..3,k1), B(k1); MFMA (M-half0, k1)
#pragma unroll
        for (int mi = 0; mi < 4; mi++) a1[mi] = ldA(bf, mi, 1);
#pragma unroll
        for (int nj = 0; nj < 4; nj++) b1[nj] = ldB(bf, nj, 1);
        issue_half(t + 1, 2);
        __builtin_amdgcn_s_barrier();
        __builtin_amdgcn_s_setprio(1);
#pragma unroll
        for (int mi = 0; mi < 4; mi++)
#pragma unroll
            for (int nj = 0; nj < 4; nj++)
                acc[mi][nj] = __builtin_amdgcn_mfma_f32_16x16x32_bf16(a1[mi], b1[nj], acc[mi][nj], 0, 0, 0);
        __builtin_amdgcn_s_setprio(0);
        __builtin_amdgcn_s_barrier();
        // ---- P3: A(4..7,k0)+A(4..7,k1); MFMA (M-half1, k0) [B(k0) still live]
#pragma unroll
        for (int mi = 0; mi < 4; mi++) a0[mi] = ldA(bf, mi + 4, 0);
#pragma unroll
        for (int mi = 0; mi < 4; mi++) a1[mi] = ldA(bf, mi + 4, 1);
        issue_half(t + 1, 3);
        __builtin_amdgcn_s_barrier();
        __builtin_amdgcn_s_setprio(1);
#pragma unroll
        for (int mi = 0; mi < 4; mi++)
#pragma unroll
            for (int nj = 0; nj < 4; nj++)
                acc[mi + 4][nj] = __builtin_amdgcn_mfma_f32_16x16x32_bf16(a0[mi], b0[nj], acc[mi + 4][nj], 0, 0, 0);
        __builtin_amdgcn_s_setprio(0);
        __builtin_amdgcn_s_barrier();
        // ---- P4: no ds_read; MFMA (M-half1, k1); per-K-tile counted vmcnt
        issue_half(t + 2, 0);
        __builtin_amdgcn_s_barrier();
        __builtin_amdgcn_s_setprio(1);
#pragma unroll
        for (int mi = 0; mi < 4; mi++)
#pragma unroll
            for (int nj = 0; nj < 4; nj++)
                acc[mi + 4][nj] = __builtin_amdgcn_mfma_f32_16x16x32_bf16(a1[mi], b1[nj], acc[mi + 4][nj], 0, 0, 0);
        __builtin_amdgcn_s_setprio(0);
        if (t + 2 < NT) {
            asm volatile("s_waitcnt vmcnt(2)" ::: "memory");  // tile t+1 landed; t+2.H0 in flight
        } else {
            asm volatile("s_waitcnt vmcnt(0)" ::: "memory");  // drain at pipeline end
        }
        __builtin_amdgcn_s_barrier();
    }

    // epilogue
#pragma unroll
    for (int nj = 0; nj < 4; nj++) {
        int col = n0 + wn + nj * 16 + l15;
        float bj = BIAS ? bias[col] : 0.f;
#pragma unroll
        for (int mi = 0; mi < 8; mi++) {
#pragma unroll
            for (int r = 0; r < 4; r++) {
                int row = m0 + wm + mi * 16 + quad * 4 + r;
                float v = acc[mi][nj][r] + bj;
                if (GELU) v = 0.5f * v * (1.0f + erff(v * 0.70710678f));
                if (OUT_BF16) outB[(size_t)row * N + col] = f2bf(v);
                else outF[(size_t)row * N + col] = v;
            }
        }
    }
}

// ---------- MFMA flash attention ----------
// qkv bf16 (B*T, 3072): q at h*64, k at 1024+h*64, v at 2048+h*64. out bf16 (B*T, 1024).
// Block: 256 thr = 4 waves. Causal work per Q-tile is proportional to qt+1 (1:16 spread), so each
// block processes TWO Q-tiles {15-bx, bx}: constant 17 units/block, 512 equal-length blocks
// (grid 8x64) -> steady 2 blocks/CU residency instead of the measured 13.6% avg occupancy.
__global__ __launch_bounds__(256, 2) void k_attn(const u16* __restrict__ qkv, u16* __restrict__ out) {
    const int b = blockIdx.y >> 4, h = blockIdx.y & 15;
    const int tid = threadIdx.x;
    const int wave = tid >> 6, lane = tid & 63;
    const int quad = lane >> 4, l15 = lane & 15;

    __shared__ __align__(16) u16 Klds[64 * 72];
    __shared__ __align__(16) u16 Vt[64 * 72];        // Vt[d][krow]
    __shared__ __align__(16) u16 Plds[4][32 * 72];   // wave-private

    const u16* base = qkv + (size_t)b * 2048 * 3072 + h * 64;

    // staging assignments
    const int kk_ = tid >> 2, kc0 = (tid & 3) * 16;  // K: row kk_, cols kc0..kc0+15
    const int vk = tid & 63, vc = (tid >> 6) * 16;   // V: row vk, cols vc..vc+15 (transposed write)

    for (int pass = 0; pass < 2; pass++) {
        const int qt = pass ? blockIdx.x : 15 - blockIdx.x;  // heavy tile first
        const int q0 = qt * 128;
        const int wrow = q0 + wave * 32;

        // Q fragments (A-layout): rows wrow+i*16+l15, k = kc*32+quad*8
        bf16x8 qf[2][2];
#pragma unroll
        for (int i = 0; i < 2; i++)
#pragma unroll
            for (int kc = 0; kc < 2; kc++)
                qf[i][kc] = *(const bf16x8*)(base + (size_t)(wrow + i * 16 + l15) * 3072 + kc * 32 + quad * 8);

        f32x4 o[2][4];
#pragma unroll
        for (int i = 0; i < 2; i++)
#pragma unroll
            for (int jd = 0; jd < 4; jd++) o[i][jd] = (f32x4){0.f, 0.f, 0.f, 0.f};
        float mrow[2][4], lrow[2][4];
#pragma unroll
        for (int i = 0; i < 2; i++)
#pragma unroll
            for (int r = 0; r < 4; r++) { mrow[i][r] = -3e38f; lrow[i][r] = 0.f; }

        const int ktiles = 2 * (qt + 1);
        for (int t = 0; t < ktiles; t++) {
            const int kt = t * 64;
            __syncthreads();
            {
                const u16* kp = base + 1024 + (size_t)(kt + kk_) * 3072 + kc0;
                uint4 a = *(const uint4*)kp;
                uint4 c = *(const uint4*)(kp + 8);
                *(uint4*)(Klds + kk_ * 72 + kc0) = a;
                *(uint4*)(Klds + kk_ * 72 + kc0 + 8) = c;
                const u16* vp = base + 2048 + (size_t)(kt + vk) * 3072 + vc;
                uint4 v0 = *(const uint4*)vp;
                uint4 v1 = *(const uint4*)(vp + 8);
                u16 tmp[16];
                *(uint4*)tmp = v0; *(uint4*)(tmp + 8) = v1;
#pragma unroll
                for (int e = 0; e < 16; e++) Vt[(vc + e) * 72 + vk] = tmp[e];
            }
            __syncthreads();

            if (kt <= wrow + 31) {
                // S = Q @ K^T
                f32x4 s[2][4];
#pragma unroll
                for (int i = 0; i < 2; i++)
#pragma unroll
                    for (int j = 0; j < 4; j++) s[i][j] = (f32x4){0.f, 0.f, 0.f, 0.f};
#pragma unroll
                for (int kc = 0; kc < 2; kc++) {
                    bf16x8 bf[4];
#pragma unroll
                    for (int j = 0; j < 4; j++)
                        bf[j] = *(const bf16x8*)(Klds + (j * 16 + l15) * 72 + kc * 32 + quad * 8);
#pragma unroll
                    for (int i = 0; i < 2; i++)
#pragma unroll
                        for (int j = 0; j < 4; j++)
                            s[i][j] = __builtin_amdgcn_mfma_f32_16x16x32_bf16(qf[i][kc], bf[j], s[i][j], 0, 0, 0);
                }
                const bool partial = (kt + 63 > wrow);
#pragma unroll
                for (int i = 0; i < 2; i++)
#pragma unroll
                    for (int j = 0; j < 4; j++)
#pragma unroll
                        for (int r = 0; r < 4; r++) {
                            float v = s[i][j][r] * 0.125f;
                            if (partial) {
                                int row = wrow + i * 16 + quad * 4 + r;
                                int col = kt + j * 16 + l15;
                                if (col > row) v = -3e30f;
                            }
                            s[i][j][r] = v;
                        }
                u16* pw = Plds[wave];
#pragma unroll
                for (int i = 0; i < 2; i++)
#pragma unroll
                    for (int r = 0; r < 4; r++) {
                        float mx = fmaxf(fmaxf(s[i][0][r], s[i][1][r]), fmaxf(s[i][2][r], s[i][3][r]));
                        mx = fmaxf(mx, __shfl_xor(mx, 1));
                        mx = fmaxf(mx, __shfl_xor(mx, 2));
                        mx = fmaxf(mx, __shfl_xor(mx, 4));
                        mx = fmaxf(mx, __shfl_xor(mx, 8));
                        float mnew = fmaxf(mrow[i][r], mx);
                        float alpha = __expf(mrow[i][r] - mnew);
                        mrow[i][r] = mnew;
                        float psum = 0.f;
#pragma unroll
                        for (int j = 0; j < 4; j++) {
                            float p = __expf(s[i][j][r] - mnew);
                            s[i][j][r] = p;
                            psum += p;
                        }
                        psum += __shfl_xor(psum, 1);
                        psum += __shfl_xor(psum, 2);
                        psum += __shfl_xor(psum, 4);
                        psum += __shfl_xor(psum, 8);
                        lrow[i][r] = lrow[i][r] * alpha + psum;
#pragma unroll
                        for (int jd = 0; jd < 4; jd++) o[i][jd][r] *= alpha;
                    }
#pragma unroll
                for (int i = 0; i < 2; i++)
#pragma unroll
                    for (int j = 0; j < 4; j++)
#pragma unroll
                        for (int r = 0; r < 4; r++)
                            pw[(i * 16 + quad * 4 + r) * 72 + j * 16 + l15] = f2bf(s[i][j][r]);
#pragma unroll
                for (int kc = 0; kc < 2; kc++) {
                    bf16x8 pa[2], vb[4];
#pragma unroll
                    for (int i = 0; i < 2; i++)
                        pa[i] = *(const bf16x8*)(pw + (i * 16 + l15) * 72 + kc * 32 + quad * 8);
#pragma unroll
                    for (int jd = 0; jd < 4; jd++)
                        vb[jd] = *(const bf16x8*)(Vt + (jd * 16 + l15) * 72 + kc * 32 + quad * 8);
#pragma unroll
                    for (int i = 0; i < 2; i++)
#pragma unroll
                        for (int jd = 0; jd < 4; jd++)
                            o[i][jd] = __builtin_amdgcn_mfma_f32_16x16x32_bf16(pa[i], vb[jd], o[i][jd], 0, 0, 0);
                }
            }
        }
        // epilogue: out[row][h*64+d] = o / l
#pragma unroll
        for (int i = 0; i < 2; i++)
#pragma unroll
            for (int r = 0; r < 4; r++) {
                float inv = 1.0f / lrow[i][r];
                size_t row = (size_t)(b * 2048 + wrow + i * 16 + quad * 4 + r);
#pragma unroll
                for (int jd = 0; jd < 4; jd++)
                    out[row * 1024 + h * 64 + jd * 16 + l15] = f2bf(o[i][jd][r] * inv);
            }
    }
}

// ---------- CE per row ----------
__global__ __launch_bounds__(256) void k_ce(const float* __restrict__ logits, const int* __restrict__ targets,
                                            float* __restrict__ ce) {
    int row = blockIdx.x, tid = threadIdx.x;
    const float4* lr = (const float4*)(logits + (size_t)row * 4096);
    float4 v[4];
#pragma unroll
    for (int c = 0; c < 4; c++) v[c] = lr[tid + c * 256];
    float mx = -3e38f;
#pragma unroll
    for (int c = 0; c < 4; c++) mx = fmaxf(mx, fmaxf(fmaxf(v[c].x, v[c].y), fmaxf(v[c].z, v[c].w)));
#pragma unroll
    for (int off = 32; off; off >>= 1) mx = fmaxf(mx, __shfl_xor(mx, off));
    __shared__ float rm[4], rsum[4];
    int wid = tid >> 6, lane = tid & 63;
    if (lane == 0) rm[wid] = mx;
    __syncthreads();
    mx = fmaxf(fmaxf(rm[0], rm[1]), fmaxf(rm[2], rm[3]));
    float se = 0.f;
#pragma unroll
    for (int c = 0; c < 4; c++)
        se += __expf(v[c].x - mx) + __expf(v[c].y - mx) + __expf(v[c].z - mx) + __expf(v[c].w - mx);
#pragma unroll
    for (int off = 32; off; off >>= 1) se += __shfl_xor(se, off);
    if (lane == 0) rsum[wid] = se;
    __syncthreads();
    if (tid == 0) {
        se = rsum[0] + rsum[1] + rsum[2] + rsum[3];
        int tgt = targets[row];
        float nll = -(logits[(size_t)row * 4096 + tgt] - mx - logf(se));
        ce[row] = (tgt == 0) ? 0.f : nll;
    }
}

// ---------- final loss ----------
__global__ __launch_bounds__(256) void k_loss(const float* __restrict__ ce, const int* __restrict__ vmask,
                                              float* __restrict__ out) {
    int tid = threadIdx.x;
    int wid = tid >> 6, lane = tid & 63;
    int bad = 0;
    for (int i = tid; i < 2048; i += 256) {
        unsigned int w = ((const unsigned int*)vmask)[i];
        if (w > 1u) bad = 1;
    }
#pragma unroll
    for (int off = 32; off; off >>= 1) bad |= __shfl_xor(bad, off);
    __shared__ int sb[4];
    if (lane == 0) sb[wid] = bad;
    __syncthreads();
    bad = sb[0] | sb[1] | sb[2] | sb[3];

    float s1 = 0.f, s2 = 0.f;
    if (bad) {
        const unsigned char* mb = (const unsigned char*)vmask;
        for (int i = tid; i < 8192; i += 256) {
            float w = 1.0f + 4.0f * (mb[i] != 0);
            s1 += ce[i] * w; s2 += w;
        }
    } else {
        for (int i = tid; i < 8192; i += 256) {
            float w = 1.0f + 4.0f * (vmask[i] != 0);
            s1 += ce[i] * w; s2 += w;
        }
    }
#pragma unroll
    for (int off = 32; off; off >>= 1) { s1 += __shfl_down(s1, off); s2 += __shfl_down(s2, off); }
    __shared__ float r1[4], r2[4];
    if (lane == 0) { r1[wid] = s1; r2[wid] = s2; }
    __syncthreads();
    if (tid == 0) out[0] = (r1[0] + r1[1] + r1[2] + r1[3]) / (r2[0] + r2[1] + r2[2] + r2[3]);
}

extern "C" void kernel_launch(void* const* d_in, const int* in_sizes, int n_in,
                              void* d_out, int out_size, void* d_ws, size_t ws_size,
                              hipStream_t stream) {
    const int* input_ids = (const int*)d_in[0];
    const int* targets = (const int*)d_in[1];
    const int* vmask = (const int*)d_in[2];
    const float* token_emb = (const float*)d_in[3];
    const float* pos_emb = (const float*)d_in[4];
    const float* ln1_w = (const float*)d_in[5];
    const float* ln1_b = (const float*)d_in[6];
    const float* wqkv = (const float*)d_in[7];
    const float* bqkv = (const float*)d_in[8];
    const float* wproj = (const float*)d_in[9];
    const float* bproj = (const float*)d_in[10];
    const float* ln2_w = (const float*)d_in[11];
    const float* ln2_b = (const float*)d_in[12];
    const float* w1 = (const float*)d_in[13];
    const float* b1 = (const float*)d_in[14];
    const float* w2 = (const float*)d_in[15];
    const float* b2 = (const float*)d_in[16];
    const float* lnf_w = (const float*)d_in[17];
    const float* lnf_b = (const float*)d_in[18];

    char* p = (char*)d_ws;
    u16* embb = (u16*)p;   p += (size_t)4096 * 1024 * 2;
    u16* wqkvt = (u16*)p;  p += (size_t)8 * 3072 * 1024 * 2;
    u16* wprojt = (u16*)p; p += (size_t)8 * 1024 * 1024 * 2;
    u16* w1t = (u16*)p;    p += (size_t)8 * 4096 * 1024 * 2;
    u16* w2t = (u16*)p;    p += (size_t)8 * 1024 * 4096 * 2;
    float* xw = (float*)p; p += (size_t)8192 * 1024 * 4;
    u16* hb = (u16*)p;     p += (size_t)8192 * 1024 * 2;
    u16* qkvb = (u16*)p;   p += (size_t)8192 * 3072 * 2;
    u16* attnb = (u16*)p;  p += (size_t)8192 * 1024 * 2;
    u16* ffb = (u16*)p;    p += (size_t)8192 * 4096 * 2;
    float* cerow = (float*)p; p += 8192 * 4;

    float* logits = (float*)d_out;

    k_cvt<<<4096, 256, 0, stream>>>(token_emb, embb);
    dim3 tb(32, 8);
    k_transpose<<<dim3(96, 32, 8), tb, 0, stream>>>(wqkv, wqkvt, 1024, 3072);
    k_transpose<<<dim3(32, 32, 8), tb, 0, stream>>>(wproj, wprojt, 1024, 1024);
    k_transpose<<<dim3(128, 32, 8), tb, 0, stream>>>(w1, w1t, 1024, 4096);
    k_transpose<<<dim3(32, 128, 8), tb, 0, stream>>>(w2, w2t, 4096, 1024);

    k_embed<<<8192, 256, 0, stream>>>(input_ids, token_emb, pos_emb, xw);

    for (int l = 0; l < 8; l++) {
        k_ln<<<8192, 256, 0, stream>>>(xw, ln1_w + l * 1024, ln1_b + l * 1024, hb);
        k_gemm256<true, false, true><<<dim3(12, 32), 512, 0, stream>>>(
            hb, wqkvt + (size_t)l * 3072 * 1024, bqkv + l * 3072, nullptr, qkvb, 8192, 3072, 1024);
        k_attn<<<dim3(8, 64), 256, 0, stream>>>(qkvb, attnb);
        k_gemm<false, false, true, true><<<dim3(8, 64), 256, 0, stream>>>(
            attnb, wprojt + (size_t)l * 1024 * 1024, bproj + l * 1024, xw, xw, nullptr, 8192, 1024, 1024);
        k_ln<<<8192, 256, 0, stream>>>(xw, ln2_w + l * 1024, ln2_b + l * 1024, hb);
        k_gemm256<true, true, true><<<dim3(16, 32), 512, 0, stream>>>(
            hb, w1t + (size_t)l * 4096 * 1024, b1 + l * 4096, nullptr, ffb, 8192, 4096, 1024);
        k_gemm<false, false, true, true><<<dim3(8, 64), 256, 0, stream>>>(
            ffb, w2t + (size_t)l * 1024 * 4096, b2 + l * 1024, xw, xw, nullptr, 8192, 1024, 4096);
    }

    k_ln<<<8192, 256, 0, stream>>>(xw, lnf_w, lnf_b, hb);
    k_gemm256<false, false, false><<<dim3(16, 32), 512, 0, stream>>>(
        hb, embb, nullptr, logits, nullptr, 8192, 4096, 1024);

    k_ce<<<8192, 256, 0, stream>>>(logits, targets, cerow);
    k_loss<<<1, 256, 0, stream>>>(cerow, vmask, logits + (size_t)8192 * 4096);
}